// Round 12
// baseline (108.654 us; speedup 1.0000x reference)
//
#include <hip/hip_runtime.h>

// src (B,C,D,H,W) f32, flow (B,3,D,H,W) f32, C==1
constexpr int B  = 2;
constexpr int D  = 160;
constexpr int H  = 192;
constexpr int W  = 224;
constexpr int HW = H * W;        // 43008
constexpr int N  = D * HW;       // 6,881,280 per volume

// Block tile: 16x * 16y * 2z = 512 voxels; 256 threads, 2 z-voxels/thread.
// Wave footprint per memory instruction: 16x * 4y (A/B vs v8's 32x * 2y).
constexpr int GX = W / 16;       // 14
constexpr int GY = H / 16;       // 12
constexpr int GZ = D / 2;        // 80
constexpr int NBLOCKS = GX * GY * GZ * B;    // 26880

typedef float f2 __attribute__((ext_vector_type(2)));
// 8-byte gather with 4-byte alignment guarantee (single global_load_dwordx2)
struct __attribute__((packed, aligned(4))) f2u { f2 v; };

__global__ __launch_bounds__(256, 8) void st3d_warp_v9(
    const float* __restrict__ src,
    const float* __restrict__ flow,
    float* __restrict__ out)
{
    const int tid = threadIdx.x;
    int tmp = blockIdx.x;
    const int bx = tmp % GX; tmp /= GX;
    const int by = tmp % GY; tmp /= GY;
    const int bz = tmp % GZ;
    const int b  = tmp / GZ;

    const int x = bx * 16 + (tid & 15);
    const int y = by * 16 + (tid >> 4);     // [0,16)
    const int zb = bz * 2;

    const float* fl = flow + (size_t)b * 3 * N;
    const float* sb = src  + (size_t)b * N;   // C == 1

    // ---- phase A: all 6 flow loads issued together (coalesced, 4 lines/instr) ----
    const int n0 = zb * HW + y * W + x;
    float dz0 = fl[n0],          dz1 = fl[n0 + HW];
    float dy0 = fl[N + n0],      dy1 = fl[N + n0 + HW];
    float dx0 = fl[2*N + n0],    dx1 = fl[2*N + n0 + HW];

    // ---- phase B: per-voxel indices/weights, then 8 independent gathers ----
    float wz0[2], wz1[2], wy0[2], wy1[2], wa[2], wb[2];
    const float* ap[2][4];
#pragma unroll
    for (int j = 0; j < 2; ++j) {
        float cz = (float)(zb + j) + (j ? dz1 : dz0);
        float cy = (float)y        + (j ? dy1 : dy0);
        float cx = (float)x        + (j ? dx1 : dx0);

        float fz0 = floorf(cz); int z0 = (int)fz0; float fz = cz - fz0;
        float fy0 = floorf(cy); int y0 = (int)fy0; float fy = cy - fy0;
        float fx0 = floorf(cx); int x0 = (int)fx0; float fx = cx - fx0;
        int z1 = z0 + 1, y1 = y0 + 1, x1 = x0 + 1;

        wz0[j] = (1.0f - fz) * ((z0 >= 0 && z0 < D) ? 1.0f : 0.0f);
        wz1[j] = fz          * ((z1 >= 0 && z1 < D) ? 1.0f : 0.0f);
        wy0[j] = (1.0f - fy) * ((y0 >= 0 && y0 < H) ? 1.0f : 0.0f);
        wy1[j] = fy          * ((y1 >= 0 && y1 < H) ? 1.0f : 0.0f);
        float wx0 = (1.0f - fx) * ((x0 >= 0 && x0 < W) ? 1.0f : 0.0f);
        float wx1 = fx          * ((x1 >= 0 && x1 < W) ? 1.0f : 0.0f);

        // x-pair base; wrong-slot cases carry weight 0 (verified per-case):
        //   x0 in [0,W-2]: wa=wx0 (slot p.x), wb=wx1 (slot p.y)
        //   x0 == -1     : pair=(0,1); corner x1=0 is p.x -> wa=wx1, wb=wx0(dead)
        //   x0 == W-1    : pair=(W-2,W-1); corner x0=W-1 is p.y -> wb=wx0, wa=wx1(dead)
        int  xp   = min(max(x0, 0), W - 2);
        bool sel0 = (x0 == xp);
        wa[j] = sel0 ? wx0 : wx1;
        wb[j] = sel0 ? wx1 : wx0;

        int zc0 = min(max(z0, 0), D - 1), zc1 = min(max(z1, 0), D - 1);
        int yc0 = min(max(y0, 0), H - 1), yc1 = min(max(y1, 0), H - 1);

        ap[j][0] = sb + zc0 * HW + yc0 * W + xp;
        ap[j][1] = sb + zc0 * HW + yc1 * W + xp;
        ap[j][2] = sb + zc1 * HW + yc0 * W + xp;
        ap[j][3] = sb + zc1 * HW + yc1 * W + xp;
    }

    // 8 independent 8B gathers — all in flight before any use
    f2 p00 = ((const f2u*)ap[0][0])->v;
    f2 p01 = ((const f2u*)ap[0][1])->v;
    f2 p02 = ((const f2u*)ap[0][2])->v;
    f2 p03 = ((const f2u*)ap[0][3])->v;
    f2 p10 = ((const f2u*)ap[1][0])->v;
    f2 p11 = ((const f2u*)ap[1][1])->v;
    f2 p12 = ((const f2u*)ap[1][2])->v;
    f2 p13 = ((const f2u*)ap[1][3])->v;

    // ---- phase C: combine + coalesced stores ----
    float f00 = p00.x * wa[0] + p00.y * wb[0];
    float f01 = p01.x * wa[0] + p01.y * wb[0];
    float f02 = p02.x * wa[0] + p02.y * wb[0];
    float f03 = p03.x * wa[0] + p03.y * wb[0];
    float acc0 = wz0[0] * (wy0[0] * f00 + wy1[0] * f01)
               + wz1[0] * (wy0[0] * f02 + wy1[0] * f03);

    float f10 = p10.x * wa[1] + p10.y * wb[1];
    float f11 = p11.x * wa[1] + p11.y * wb[1];
    float f12 = p12.x * wa[1] + p12.y * wb[1];
    float f13 = p13.x * wa[1] + p13.y * wb[1];
    float acc1 = wz0[1] * (wy0[1] * f10 + wy1[1] * f11)
               + wz1[1] * (wy0[1] * f12 + wy1[1] * f13);

    out[(size_t)b * N + n0]      = acc0;
    out[(size_t)b * N + n0 + HW] = acc1;
}

extern "C" void kernel_launch(void* const* d_in, const int* in_sizes, int n_in,
                              void* d_out, int out_size, void* d_ws, size_t ws_size,
                              hipStream_t stream)
{
    const float* src  = (const float*)d_in[0];
    const float* flow = (const float*)d_in[1];
    float* out = (float*)d_out;

    st3d_warp_v9<<<NBLOCKS, 256, 0, stream>>>(src, flow, out);
}